// Round 1
// baseline (174.830 us; speedup 1.0000x reference)
//
#include <hip/hip_runtime.h>
#include <cstddef>

constexpr int Bn = 16, Dn = 512, Nn = 4096, Kn = 64;
constexpr float FEPS = 1e-12f;

// ---------------------------------------------------------------------------
// Kernel A: fused x-norm + 1x1-conv logits + softmax over K.
//   grid 512: b = bid>>5, n-tile of 128 = (bid&31)*128. 256 threads.
//   thread = (kg 0..7) x (ng 0..31): owns 8 k x 4 n outputs.
// Writes: assign[b][k][n] (unscaled softmax), invn[b][n] = 1/max(||x||,eps)
// ---------------------------------------------------------------------------
__global__ __launch_bounds__(256) void kA(const float* __restrict__ x,
                                          const float* __restrict__ conv_w,
                                          const float* __restrict__ conv_b,
                                          float* __restrict__ assign,
                                          float* __restrict__ invn) {
  __shared__ __align__(16) float xs[32 * 128];   // [d=32][n=128]
  __shared__ __align__(16) float ws[64 * 32];    // [k=64][d=32], XOR-swizzled
  __shared__ float cb[64];
  __shared__ float red[8 * 128];
  const int tid = threadIdx.x;
  const int b = blockIdx.x >> 5;
  const int n0 = (blockIdx.x & 31) << 7;
  if (tid < 64) cb[tid] = conv_b[tid];
  const int ng = tid & 31;   // n = n0 + ng*4 + i
  const int kg = tid >> 5;   // k = kg*8 + j
  float acc[8][4];
#pragma unroll
  for (int j = 0; j < 8; ++j)
#pragma unroll
    for (int i = 0; i < 4; ++i) acc[j][i] = 0.f;
  float ss[4] = {0.f, 0.f, 0.f, 0.f};
  const float* xb = x + (size_t)b * Dn * Nn;

  for (int d0 = 0; d0 < Dn; d0 += 32) {
    if (d0) __syncthreads();
    {  // stage W chunk [64][32], swizzle col ^= ((k>>3)&7)<<2
      const int c4 = (tid & 7) << 2;
      const int k0 = tid >> 3;
#pragma unroll
      for (int i = 0; i < 2; ++i) {
        const int k = k0 + 32 * i;
        float4 v = *(const float4*)(conv_w + k * Dn + d0 + c4);
        const int sw = ((k >> 3) & 7) << 2;
        *(float4*)(ws + k * 32 + (c4 ^ sw)) = v;
      }
    }
    {  // stage x chunk [32][128] (dense, no swizzle needed)
      const int c4 = (tid & 31) << 2;
      const int r0 = tid >> 5;
#pragma unroll
      for (int i = 0; i < 4; ++i) {
        const int r = r0 + 8 * i;
        float4 v = *(const float4*)(xb + (size_t)(d0 + r) * Nn + n0 + c4);
        *(float4*)(xs + r * 128 + c4) = v;
      }
    }
    __syncthreads();
    const int wsw = kg << 2;
#pragma unroll
    for (int dd = 0; dd < 32; dd += 4) {
      float4 w4[8], x4[4];
#pragma unroll
      for (int j = 0; j < 8; ++j)
        w4[j] = *(const float4*)(ws + (kg * 8 + j) * 32 + (dd ^ wsw));
#pragma unroll
      for (int di = 0; di < 4; ++di)
        x4[di] = *(const float4*)(xs + (dd + di) * 128 + (ng << 2));
#pragma unroll
      for (int di = 0; di < 4; ++di) {
        const float* xv = (const float*)&x4[di];
#pragma unroll
        for (int i = 0; i < 4; ++i) ss[i] = fmaf(xv[i], xv[i], ss[i]);
#pragma unroll
        for (int j = 0; j < 8; ++j) {
          const float w = ((const float*)&w4[j])[di];
#pragma unroll
          for (int i = 0; i < 4; ++i) acc[j][i] = fmaf(w, xv[i], acc[j][i]);
        }
      }
    }
  }

  // ---- epilogue: invn, logits, softmax over K (cross-kg via LDS) ----
  float invv[4];
#pragma unroll
  for (int i = 0; i < 4; ++i) invv[i] = 1.f / fmaxf(sqrtf(ss[i]), FEPS);
  float lg[8][4];
#pragma unroll
  for (int j = 0; j < 8; ++j) {
    const float bk = cb[kg * 8 + j];
#pragma unroll
    for (int i = 0; i < 4; ++i) lg[j][i] = fmaf(acc[j][i], invv[i], bk);
  }
  float mx[4];
#pragma unroll
  for (int i = 0; i < 4; ++i) {
    mx[i] = lg[0][i];
#pragma unroll
    for (int j = 1; j < 8; ++j) mx[i] = fmaxf(mx[i], lg[j][i]);
  }
  __syncthreads();  // main-loop LDS traffic done before red reuse pattern
#pragma unroll
  for (int i = 0; i < 4; ++i) red[kg * 128 + (ng << 2) + i] = mx[i];
  __syncthreads();
#pragma unroll
  for (int i = 0; i < 4; ++i) {
#pragma unroll
    for (int kg2 = 0; kg2 < 8; ++kg2)
      mx[i] = fmaxf(mx[i], red[kg2 * 128 + (ng << 2) + i]);
  }
  __syncthreads();
  float ex[8][4];
  float sm[4] = {0.f, 0.f, 0.f, 0.f};
#pragma unroll
  for (int j = 0; j < 8; ++j)
#pragma unroll
    for (int i = 0; i < 4; ++i) {
      ex[j][i] = expf(lg[j][i] - mx[i]);
      sm[i] += ex[j][i];
    }
#pragma unroll
  for (int i = 0; i < 4; ++i) red[kg * 128 + (ng << 2) + i] = sm[i];
  __syncthreads();
#pragma unroll
  for (int i = 0; i < 4; ++i) {
    float t = 0.f;
#pragma unroll
    for (int kg2 = 0; kg2 < 8; ++kg2) t += red[kg2 * 128 + (ng << 2) + i];
    sm[i] = 1.f / t;
  }
  float* ab = assign + (size_t)b * Kn * Nn;
#pragma unroll
  for (int j = 0; j < 8; ++j) {
    const int k = kg * 8 + j;
    float4 v = make_float4(ex[j][0] * sm[0], ex[j][1] * sm[1],
                           ex[j][2] * sm[2], ex[j][3] * sm[3]);
    *(float4*)(ab + (size_t)k * Nn + n0 + (ng << 2)) = v;
  }
  if (kg == 0) {
    float4 v = make_float4(invv[0], invv[1], invv[2], invv[3]);
    *(float4*)(invn + (size_t)b * Nn + n0 + (ng << 2)) = v;
  }
}

// ---------------------------------------------------------------------------
// Kernel B: agg partial GEMM. agg[b,k,d] = sum_n assign[k,n]*invn[n]*x[d,n]
//   grid 512: b = bid>>5; dt = (bid&31)>>3 (d-tile of 128); seg = bid&7 (n/8)
//   thread = (kg 0..15) x (dg 0..15): owns 4 k x 8 d.
// Writes: aggp[seg][b][k][d] partial sums (deterministic, no atomics).
// ---------------------------------------------------------------------------
__global__ __launch_bounds__(256) void kB(const float* __restrict__ x,
                                          const float* __restrict__ assign,
                                          const float* __restrict__ invn,
                                          float* __restrict__ aggp) {
  __shared__ __align__(16) float as_[64 * 32];   // [k][n], swizzled
  __shared__ __align__(16) float xs[128 * 32];   // [d][n], swizzled
  __shared__ float invL[512];
  const int tid = threadIdx.x;
  const int b = blockIdx.x >> 5;
  const int rr = blockIdx.x & 31;
  const int dt = rr >> 3;
  const int seg = rr & 7;
  const int nbase = seg * 512;
  invL[tid] = invn[(size_t)b * Nn + nbase + tid];
  invL[tid + 256] = invn[(size_t)b * Nn + nbase + 256 + tid];
  const int dg = tid & 15;   // d = dt*128 + dg*8 + i
  const int kg = tid >> 4;   // k = kg*4 + j
  float acc[4][8];
#pragma unroll
  for (int j = 0; j < 4; ++j)
#pragma unroll
    for (int i = 0; i < 8; ++i) acc[j][i] = 0.f;
  const float* xb = x + (size_t)b * Dn * Nn + (size_t)(dt * 128) * Nn;
  const float* ab = assign + (size_t)b * Kn * Nn;

  for (int nc = 0; nc < 512; nc += 32) {
    __syncthreads();
    {  // stage assign [64][32] scaled by invn, swizzle ^= ((k>>2)&7)<<2
      const int c4 = (tid & 7) << 2;
      const int k0 = tid >> 3;
#pragma unroll
      for (int i = 0; i < 2; ++i) {
        const int k = k0 + 32 * i;
        float4 v = *(const float4*)(ab + (size_t)k * Nn + nbase + nc + c4);
        float4 iv = *(const float4*)(invL + nc + c4);
        v.x *= iv.x; v.y *= iv.y; v.z *= iv.z; v.w *= iv.w;
        const int sw = ((k >> 2) & 7) << 2;
        *(float4*)(as_ + k * 32 + (c4 ^ sw)) = v;
      }
    }
    {  // stage x [128][32], swizzle ^= ((r>>3)&7)<<2
      const int c4 = (tid & 7) << 2;
      const int r0 = tid >> 3;
#pragma unroll
      for (int i = 0; i < 4; ++i) {
        const int r = r0 + 32 * i;
        float4 v = *(const float4*)(xb + (size_t)r * Nn + nbase + nc + c4);
        const int sw = ((r >> 3) & 7) << 2;
        *(float4*)(xs + r * 32 + (c4 ^ sw)) = v;
      }
    }
    __syncthreads();
    const int asw = (kg & 7) << 2;
    const int xsw = (dg & 7) << 2;
#pragma unroll
    for (int cc = 0; cc < 32; cc += 4) {
      float4 a4[4], x4[8];
#pragma unroll
      for (int j = 0; j < 4; ++j)
        a4[j] = *(const float4*)(as_ + (kg * 4 + j) * 32 + (cc ^ asw));
#pragma unroll
      for (int i = 0; i < 8; ++i)
        x4[i] = *(const float4*)(xs + (dg * 8 + i) * 32 + (cc ^ xsw));
#pragma unroll
      for (int m = 0; m < 4; ++m) {
#pragma unroll
        for (int j = 0; j < 4; ++j) {
          const float a = ((const float*)&a4[j])[m];
#pragma unroll
          for (int i = 0; i < 8; ++i)
            acc[j][i] = fmaf(a, ((const float*)&x4[i])[m], acc[j][i]);
        }
      }
    }
  }
  float* outb = aggp + ((size_t)(seg * Bn + b)) * Kn * Dn;
#pragma unroll
  for (int j = 0; j < 4; ++j) {
    const int k = kg * 4 + j;
    float* p = outb + (size_t)k * Dn + dt * 128 + dg * 8;
    *(float4*)p = make_float4(acc[j][0], acc[j][1], acc[j][2], acc[j][3]);
    *(float4*)(p + 4) = make_float4(acc[j][4], acc[j][5], acc[j][6], acc[j][7]);
  }
}

// ---------------------------------------------------------------------------
// Kernel C1: per (b,k) row: mass = sum_n assign; vlad = sum(aggp) - mass*c;
// intra-normalize over d; write out; store post-norm row sumsq.
// ---------------------------------------------------------------------------
__device__ __forceinline__ float blockReduceSum(float v, float* sb) {
#pragma unroll
  for (int off = 32; off > 0; off >>= 1) v += __shfl_down(v, off, 64);
  const int lane = threadIdx.x & 63, w = threadIdx.x >> 6;
  if (lane == 0) sb[w] = v;
  __syncthreads();
  if (threadIdx.x == 0) sb[4] = sb[0] + sb[1] + sb[2] + sb[3];
  __syncthreads();
  return sb[4];
}

__global__ __launch_bounds__(256) void kC1(const float* __restrict__ assign,
                                           const float* __restrict__ aggp,
                                           const float* __restrict__ centroids,
                                           float* __restrict__ out,
                                           float* __restrict__ rowsq) {
  __shared__ float sb[5];
  const int tid = threadIdx.x;
  const int b = blockIdx.x >> 6, k = blockIdx.x & 63;
  const float* arow = assign + ((size_t)b * Kn + k) * Nn;
  float s = 0.f;
  for (int t = tid; t < Nn; t += 256) s += arow[t];
  const float mass = blockReduceSum(s, sb);
  float v[2];
  float sq = 0.f;
#pragma unroll
  for (int u = 0; u < 2; ++u) {
    const int d = tid + (u << 8);
    float val = -mass * centroids[k * Dn + d];
#pragma unroll
    for (int seg = 0; seg < 8; ++seg)
      val += aggp[(((size_t)seg * Bn + b) * Kn + k) * Dn + d];
    v[u] = val;
    sq = fmaf(val, val, sq);
  }
  const float rsq = blockReduceSum(sq, sb);
  const float inv = 1.f / fmaxf(sqrtf(rsq), FEPS);
#pragma unroll
  for (int u = 0; u < 2; ++u)
    out[((size_t)b * Kn + k) * Dn + tid + (u << 8)] = v[u] * inv;
  if (tid == 0) rowsq[b * Kn + k] = rsq * inv * inv;
}

// ---------------------------------------------------------------------------
// Kernel C2: final global L2 norm per batch (numerically, to match ref).
// ---------------------------------------------------------------------------
__global__ __launch_bounds__(256) void kC2(float* __restrict__ out,
                                           const float* __restrict__ rowsq) {
  __shared__ float sg;
  const int b = blockIdx.x, tid = threadIdx.x;
  float v = (tid < 64) ? rowsq[b * Kn + tid] : 0.f;
  if (tid < 64) {
#pragma unroll
    for (int off = 32; off > 0; off >>= 1) v += __shfl_down(v, off, 64);
  }
  if (tid == 0) sg = 1.f / fmaxf(sqrtf(v), FEPS);
  __syncthreads();
  const float inv = sg;
  float* ob = out + (size_t)b * (Kn * Dn);
  for (int t = tid; t < Kn * Dn; t += 256) ob[t] *= inv;
}

// ---------------------------------------------------------------------------
extern "C" void kernel_launch(void* const* d_in, const int* in_sizes, int n_in,
                              void* d_out, int out_size, void* d_ws,
                              size_t ws_size, hipStream_t stream) {
  const float* x = (const float*)d_in[0];
  const float* centroids = (const float*)d_in[1];
  const float* conv_w = (const float*)d_in[2];
  const float* conv_b = (const float*)d_in[3];
  float* out = (float*)d_out;
  float* ws = (float*)d_ws;
  // ws layout (floats): assign 4,194,304 | invn 65,536 | aggp 4,194,304 | rowsq 1,024
  float* assign = ws;
  float* invn = ws + 4194304;
  float* aggp = ws + 4259840;
  float* rowsq = ws + 8454144;

  kA<<<512, 256, 0, stream>>>(x, conv_w, conv_b, assign, invn);
  kB<<<512, 256, 0, stream>>>(x, assign, invn, aggp);
  kC1<<<1024, 256, 0, stream>>>(assign, aggp, centroids, out, rowsq);
  kC2<<<16, 256, 0, stream>>>(out, rowsq);
}